// Round 6
// baseline (310.308 us; speedup 1.0000x reference)
//
#include <hip/hip_runtime.h>

// Problem constants
#define NB 4
#define NC 32
#define NPIX 262144   // 512*512
#define NI 8
#define NE 512
#define FEPS 1e-12f
#define NSH 8         // atomic shards for psums

// Workspace layout (float offsets)
#define WS_HINGE  1056     // [32]
#define WS_EDGE   1088     // [1]
#define WS_PSUM   1152     // [8 shards][4*8*32] = 8192
#define WS_PCNT   9344     // [8 shards][32] = 256
#define WS_ZERO_N 9600
#define WS_SEL    10240    // int [4*8*512] = 16384
#define WS_EB     28672    // bf16 [16384][32] = 524288 shorts = 262144 floats
#define WS_SQ     294912   // [16384]

typedef __bf16 bf16x8 __attribute__((ext_vector_type(8)));
typedef float  f32x4  __attribute__((ext_vector_type(4)));

static __device__ __forceinline__ unsigned short f2bf(float x) {
    unsigned u = __builtin_bit_cast(unsigned, x);
    u += 0x7FFF + ((u >> 16) & 1);          // RNE
    return (unsigned short)(u >> 16);
}

// Async global->LDS, 16B per lane (wave writes base + lane*16, contiguous 1KB).
static __device__ __forceinline__ void gload16(const float* g, float* l) {
    __builtin_amdgcn_global_load_lds(
        (const __attribute__((address_space(1))) void*)g,
        (__attribute__((address_space(3))) void*)l,
        16, 0, 0);
}

__global__ __launch_bounds__(256) void k_zero(float* __restrict__ ws) {
    int i = blockIdx.x * 256 + threadIdx.x;
    if (i < WS_ZERO_N) ws[i] = 0.f;
}

// Pass 1 via MFMA with global_load_lds staging.
// Grid 4096 = 4 img x 1024 chunks(256 px). Wave = 64 px, all 32 ch.
// LDS per wave 8KB laid out [pxq(16)][ch(32)][4px f32]: gload g covers rows
// 2g,2g+1 (lane L -> pxq=2g+(L>>5), ch=L&31, px 4pxq..+3).
// MFMA (K=px slice of 32): A = one-hot masks (row=bin), B[k=px][col=ch] read
// as 2x ds_read_b128 per fragment (8 lanes per 4-bank slot: conflict-free).
__global__ __launch_bounds__(256, 4) void k_seg_sums(const float* __restrict__ feat,
                                                     const int* __restrict__ lab,
                                                     float* __restrict__ psums,
                                                     float* __restrict__ pcnts) {
    __shared__ float stg[4][2048];       // 4 waves x 8KB
    __shared__ float sred[4][NI][33];
    __shared__ float cred[4][NI];
    int tid = threadIdx.x, lane = tid & 63, w = tid >> 6;
    int blk = blockIdx.x;
    int b = blk >> 10;
    int p0 = (blk & 1023) * 256 + w * 64;
    int kg = lane >> 4, rc = lane & 15;

    const float* fb = feat + (size_t)b * NC * NPIX;
    const float* gp = fb + (size_t)(lane & 31) * NPIX + p0 + (lane >> 5) * 4;
    float* lp = &stg[w][0];
#pragma unroll
    for (int g = 0; g < 8; g++) gload16(gp + g * 8, lp + g * 256);

    const int* lb = lab + (size_t)b * NPIX + p0 + kg * 8;
    int4 la0 = *(const int4*)(lb);
    int4 lc0 = *(const int4*)(lb + 4);
    int4 la1 = *(const int4*)(lb + 32);
    int4 lc1 = *(const int4*)(lb + 36);

    asm volatile("s_waitcnt vmcnt(0)" ::: "memory");

    f32x4 acc0 = {0.f, 0.f, 0.f, 0.f}, acc1 = {0.f, 0.f, 0.f, 0.f};
    float cnt = 0.f;
#pragma unroll
    for (int ks = 0; ks < 2; ks++) {
        int4 la = ks ? la1 : la0;
        int4 lc = ks ? lc1 : lc0;
        uint4 mu;
        mu.x = (la.x == rc ? 0x3F80u : 0u) | (la.y == rc ? 0x3F800000u : 0u);
        mu.y = (la.z == rc ? 0x3F80u : 0u) | (la.w == rc ? 0x3F800000u : 0u);
        mu.z = (lc.x == rc ? 0x3F80u : 0u) | (lc.y == rc ? 0x3F800000u : 0u);
        mu.w = (lc.z == rc ? 0x3F80u : 0u) | (lc.w == rc ? 0x3F800000u : 0u);
        cnt += (float)((la.x == rc) + (la.y == rc) + (la.z == rc) + (la.w == rc)
                     + (lc.x == rc) + (lc.y == rc) + (lc.z == rc) + (lc.w == rc));
        bf16x8 af = __builtin_bit_cast(bf16x8, mu);
        const float* c0 = lp + (ks * 8 + kg * 2) * 128 + rc * 4;
        float4 x0 = *(const float4*)(c0);          // ch=rc,    px j0..3
        float4 x1 = *(const float4*)(c0 + 128);    // ch=rc,    px j4..7
        float4 y0 = *(const float4*)(c0 + 64);     // ch=rc+16, px j0..3
        float4 y1 = *(const float4*)(c0 + 192);    // ch=rc+16, px j4..7
        bf16x8 bf0 = {(__bf16)x0.x, (__bf16)x0.y, (__bf16)x0.z, (__bf16)x0.w,
                      (__bf16)x1.x, (__bf16)x1.y, (__bf16)x1.z, (__bf16)x1.w};
        bf16x8 bf1 = {(__bf16)y0.x, (__bf16)y0.y, (__bf16)y0.z, (__bf16)y0.w,
                      (__bf16)y1.x, (__bf16)y1.y, (__bf16)y1.z, (__bf16)y1.w};
        acc0 = __builtin_amdgcn_mfma_f32_16x16x32_bf16(af, bf0, acc0, 0, 0, 0);
        acc1 = __builtin_amdgcn_mfma_f32_16x16x32_bf16(af, bf1, acc1, 0, 0, 0);
    }

    // D layout: col=lane&15, row=(lane>>4)*4+rg. Bins = rows 0-7 -> lanes 0-31.
    if (lane < 32) {
#pragma unroll
        for (int rg = 0; rg < 4; rg++) {
            int row = (lane >> 4) * 4 + rg;
            sred[w][row][rc] = acc0[rg];
            sred[w][row][16 + rc] = acc1[rg];
        }
    }
    cnt += __shfl_xor(cnt, 16);
    cnt += __shfl_xor(cnt, 32);
    if (lane < 8) cred[w][lane] = cnt;
    __syncthreads();

    int sh = blk & (NSH - 1);
    {
        int bin = tid >> 5, ch = tid & 31;
        float s = sred[0][bin][ch] + sred[1][bin][ch] + sred[2][bin][ch] + sred[3][bin][ch];
        atomicAdd(&psums[sh * (NB * NI * NC) + ((size_t)b * NI + bin) * NC + ch], s);
    }
    if (tid < 8)
        atomicAdd(&pcnts[sh * (NB * NI) + b * NI + tid],
                  cred[0][tid] + cred[1][tid] + cred[2][tid] + cred[3][tid]);
}

// Pass 2 with global_load_lds staging. Grid 4096 = 4 img x 1024 chunks(256 px).
// Wave = 64 px (1 px/lane). LDS per wave 8KB laid out [ch(32)][px(64)]:
// gload g covers ch 4g..4g+3 (lane L -> ch=4g+(L>>4), px (L&15)*4..+3).
// Consume: lane=px, stride-1 ds_read per ch (2-way bank alias = free).
__global__ __launch_bounds__(256, 4) void k_var(const float* __restrict__ feat,
                                                const int* __restrict__ lab,
                                                const float* __restrict__ psums,
                                                const float* __restrict__ pcnts,
                                                float* __restrict__ hinge) {
    __shared__ float stg[4][2048];
    __shared__ float mlds[NI][33];
    __shared__ float hred[4][8];
    int tid = threadIdx.x, lane = tid & 63, w = tid >> 6;
    int blk = blockIdx.x;
    int b = blk >> 10;
    int p0 = (blk & 1023) * 256 + w * 64;

    {   // means first, so the barrier's implicit vmcnt-drain costs nothing extra
        int bin = tid >> 5, ch = tid & 31;
        float s = 0.f, c = 0.f;
#pragma unroll
        for (int sh = 0; sh < NSH; sh++) {
            s += psums[sh * (NB * NI * NC) + ((size_t)b * NI + bin) * NC + ch];
            c += pcnts[sh * (NB * NI) + b * NI + bin];
        }
        mlds[bin][ch] = s / c;
    }
    __syncthreads();

    const float* gp = feat + (size_t)b * NC * NPIX + (size_t)(lane >> 4) * NPIX
                    + p0 + (lane & 15) * 4;
    float* lp = &stg[w][0];
#pragma unroll
    for (int g = 0; g < 8; g++) gload16(gp + (size_t)g * 4 * NPIX, lp + g * 256);

    int lv = lab[(size_t)b * NPIX + p0 + lane];

    asm volatile("s_waitcnt vmcnt(0)" ::: "memory");

    float a0 = 0.f;
#pragma unroll
    for (int c = 0; c < NC; c++) {
        float d = lp[c * 64 + lane] - mlds[lv][c];
        a0 += d * d;
    }
    float t = fmaxf(sqrtf(a0 + FEPS) - 0.5f, 0.f);
    float h0 = t * t;

    float hacc[8];
#pragma unroll
    for (int bin = 0; bin < 8; bin++) hacc[bin] = (lv == bin) ? h0 : 0.f;
#pragma unroll
    for (int m = 8; m <= 32; m <<= 1) {
#pragma unroll
        for (int bin = 0; bin < 8; bin++) hacc[bin] += __shfl_xor(hacc[bin], m);
    }
#pragma unroll
    for (int half = 4; half >= 1; half >>= 1) {
#pragma unroll
        for (int k = 0; k < half; k++) {
            float t0 = __shfl_xor(hacc[k], half);
            float t1 = __shfl_xor(hacc[k + half], half);
            hacc[k] = (lane & half) ? (hacc[k + half] + t1) : (hacc[k] + t0);
        }
    }
    if (lane < 8) hred[w][lane] = hacc[0];
    __syncthreads();
    if (tid < 8)
        atomicAdd(&hinge[b * NI + tid],
                  hred[0][tid] + hred[1][tid] + hred[2][tid] + hred[3][tid]);
}

// Ordered "first 512 pixels with labelEdges==i" per (b,i). One wave per pair.
__global__ __launch_bounds__(64) void k_sel(const int* __restrict__ le, int* __restrict__ sel) {
    int inst = blockIdx.x & 7;
    int b = blockIdx.x >> 3;
    int lane = threadIdx.x;
    const int* lp = le + (size_t)b * NPIX;
    int* sp = sel + blockIdx.x * NE;
    int s = 0;
    for (int base = 0; base < NPIX && s < NE; base += 256) {
        int4 l = *(const int4*)(lp + base + lane * 4);
        int m0 = (l.x == inst), m1 = (l.y == inst), m2 = (l.z == inst), m3 = (l.w == inst);
        int cnt = m0 + m1 + m2 + m3;
        int incl = cnt;
#pragma unroll
        for (int off = 1; off < 64; off <<= 1) {
            int t = __shfl_up(incl, off);
            if (lane >= off) incl += t;
        }
        int r = incl - cnt;
        int pbase = base + lane * 4;
        if (m0) { if (s + r < NE) sp[s + r] = pbase + 0; r++; }
        if (m1) { if (s + r < NE) sp[s + r] = pbase + 1; r++; }
        if (m2) { if (s + r < NE) sp[s + r] = pbase + 2; r++; }
        if (m3) { if (s + r < NE) sp[s + r] = pbase + 3; r++; }
        s += __shfl(incl, 63);
    }
    for (int idx = s + lane; idx < NE; idx += 64) sp[idx] = 0;  // safety, never expected
}

// Gather edge rows -> bf16 [16384][32] + f32 sq norms.
__global__ __launch_bounds__(256) void k_gather(const float* __restrict__ feat,
                                                const int* __restrict__ sel,
                                                short* __restrict__ ebh,
                                                float* __restrict__ sq) {
    int oct = blockIdx.x;         // 0..7
    int bi = blockIdx.y;          // 0..31 = b*8+i
    int b = bi >> 3;
    int tid = threadIdx.x;
    int rrel = tid >> 2, qc = tid & 3;
    int r = bi * NE + oct * 64 + rrel;
    int p = sel[r];
    const float* fp = feat + (size_t)b * NC * NPIX + p;
    int c0 = qc * 8;
    float s = 0.f;
    int pk[4];
#pragma unroll
    for (int j = 0; j < 4; j++) {
        float v0 = fp[(size_t)(c0 + 2 * j) * NPIX];
        float v1 = fp[(size_t)(c0 + 2 * j + 1) * NPIX];
        s += v0 * v0 + v1 * v1;
        pk[j] = (unsigned)f2bf(v0) | ((unsigned)f2bf(v1) << 16);
    }
    *(int4*)(ebh + (size_t)r * NC + c0) = make_int4(pk[0], pk[1], pk[2], pk[3]);
    s += __shfl_xor(s, 1);
    s += __shfl_xor(s, 2);
    if (qc == 0) sq[r] = s;
}

// Edge pair loss via MFMA (16x16x32 bf16, K=32=NC in one instruction).
__global__ __launch_bounds__(256) void k_edge(const short* __restrict__ ebh,
                                              const float* __restrict__ sq,
                                              float* __restrict__ edge_acc) {
    __shared__ float sqa[128], sqb[128];
    __shared__ float wsum[4];
    int tid = threadIdx.x;
    int lane = tid & 63, w = tid >> 6;
    int ti = blockIdx.x >> 2, tj = blockIdx.x & 3;
    int q = blockIdx.y;       // 0..27
    int b = blockIdx.z;
    int pi = 0, pj = 0, k = q;
    for (int i = 0; i < 8; i++) { int row = 7 - i; if (k < row) { pi = i; pj = i + 1 + k; break; } k -= row; }
    int base_a = b * 4096 + pi * NE + ti * 128;
    int base_b = b * 4096 + pj * NE + tj * 128;

    if (tid < 128) sqa[tid] = sq[base_a + tid];
    else sqb[tid - 128] = sq[base_b + tid - 128];
    __syncthreads();

    int lrow = lane & 15;
    int lk = (lane >> 4) * 8;

    bf16x8 a[2];
#pragma unroll
    for (int u = 0; u < 2; u++)
        a[u] = *(const bf16x8*)(ebh + (size_t)(base_a + w * 32 + u * 16 + lrow) * NC + lk);
    bf16x8 bb[8];
#pragma unroll
    for (int v = 0; v < 8; v++)
        bb[v] = *(const bf16x8*)(ebh + (size_t)(base_b + v * 16 + lrow) * NC + lk);

    f32x4 acc[2][8];
#pragma unroll
    for (int u = 0; u < 2; u++)
#pragma unroll
        for (int v = 0; v < 8; v++) acc[u][v] = (f32x4){0.f, 0.f, 0.f, 0.f};

#pragma unroll
    for (int u = 0; u < 2; u++)
#pragma unroll
        for (int v = 0; v < 8; v++)
            acc[u][v] = __builtin_amdgcn_mfma_f32_16x16x32_bf16(a[u], bb[v], acc[u][v], 0, 0, 0);

    float lsum = 0.f;
    int orow0 = w * 32 + (lane >> 4) * 4;
    int ocol = lane & 15;
#pragma unroll
    for (int u = 0; u < 2; u++) {
#pragma unroll
        for (int v = 0; v < 8; v++) {
            float sb = sqb[v * 16 + ocol];
#pragma unroll
            for (int rg = 0; rg < 4; rg++) {
                float d2 = sqa[orow0 + u * 16 + rg] + sb - 2.f * acc[u][v][rg];
                float pd = sqrtf(fmaxf(d2, 0.f) + FEPS);
                float t = 2.f - pd;                  // 2*(DD-DV)
                if (t > 0.f) lsum += t * t;
            }
        }
    }
#pragma unroll
    for (int off = 32; off > 0; off >>= 1) lsum += __shfl_xor(lsum, off);
    if (lane == 0) wsum[w] = lsum;
    __syncthreads();
    if (tid == 0) atomicAdd(edge_acc, wsum[0] + wsum[1] + wsum[2] + wsum[3]);
}

// Final combine (sums/cnts reduced from shards here): var, dist, edge, reg, total.
__global__ __launch_bounds__(256) void k_final(const float* __restrict__ psums,
                                               const float* __restrict__ pcnts,
                                               const float* __restrict__ hinge,
                                               const float* __restrict__ edge_acc,
                                               float* __restrict__ out) {
    __shared__ float m[NB * NI * NC];
    __shared__ float cshr[NB * NI];
    __shared__ float accs[3];   // var, dist, reg
    int tid = threadIdx.x;
    if (tid < 3) accs[tid] = 0.f;
    if (tid < NB * NI) {
        float c = 0.f;
#pragma unroll
        for (int sh = 0; sh < NSH; sh++) c += pcnts[sh * (NB * NI) + tid];
        cshr[tid] = c;
    }
    __syncthreads();
    for (int i = tid; i < NB * NI * NC; i += 256) {
        float s = 0.f;
#pragma unroll
        for (int sh = 0; sh < NSH; sh++) s += psums[sh * (NB * NI * NC) + i];
        m[i] = s / cshr[i >> 5];
    }
    __syncthreads();

    float var_p = 0.f, dist_p = 0.f, reg_p = 0.f;
    if (tid < 32) {   // (b, i)
        var_p = hinge[tid] / cshr[tid] * (1.f / 8.f);
        const float* mm = &m[tid * NC];
        float s = 0.f;
        for (int c = 0; c < NC; c++) s += mm[c] * mm[c];
        reg_p = sqrtf(s + FEPS) * (0.001f / 8.f);   // DELTA / N
    }
    if (tid < NB * 28) {
        int b = tid / 28, q = tid % 28;
        int pi = 0, pj = 0, k = q;
        for (int i = 0; i < 8; i++) { int row = 7 - i; if (k < row) { pi = i; pj = i + 1 + k; break; } k -= row; }
        const float* ma = &m[(b * NI + pi) * NC];
        const float* mb = &m[(b * NI + pj) * NC];
        float s = 0.f;
        for (int c = 0; c < NC; c++) { float d = ma[c] - mb[c]; s += d * d; }
        float dm = sqrtf(s + FEPS);
        float t = fmaxf(3.0f - dm, 0.f);   // 2*DD - dm
        dist_p = t * t * (1.f / 56.f);
    }
    atomicAdd(&accs[0], var_p);
    atomicAdd(&accs[1], dist_p);
    atomicAdd(&accs[2], reg_p);
    __syncthreads();
    if (tid == 0) {
        float var = accs[0], dist = accs[1], reg = accs[2];
        float edge = edge_acc[0] * (1.f / (512.f * 512.f * 56.f));
        out[0] = var + dist + edge + reg;
        out[1] = var;
        out[2] = dist;
        out[3] = edge;
        out[4] = reg;
    }
}

extern "C" void kernel_launch(void* const* d_in, const int* in_sizes, int n_in,
                              void* d_out, int out_size, void* d_ws, size_t ws_size,
                              hipStream_t stream) {
    const float* feat   = (const float*)d_in[0];
    const int*   labels = (const int*)d_in[1];
    const int*   le     = (const int*)d_in[2];
    float* out = (float*)d_out;
    float* ws  = (float*)d_ws;

    float* hinge = ws + WS_HINGE;
    float* edge  = ws + WS_EDGE;
    float* psums = ws + WS_PSUM;
    float* pcnts = ws + WS_PCNT;
    int*   sel   = (int*)(ws + WS_SEL);
    short* ebh   = (short*)(ws + WS_EB);
    float* sq    = ws + WS_SQ;

    hipLaunchKernelGGL(k_zero,     dim3(38),          dim3(256), 0, stream, ws);
    hipLaunchKernelGGL(k_seg_sums, dim3(4096),        dim3(256), 0, stream, feat, labels, psums, pcnts);
    hipLaunchKernelGGL(k_var,      dim3(4096),        dim3(256), 0, stream, feat, labels, psums, pcnts, hinge);
    hipLaunchKernelGGL(k_sel,      dim3(32),          dim3(64),  0, stream, le, sel);
    hipLaunchKernelGGL(k_gather,   dim3(8, 32),       dim3(256), 0, stream, feat, sel, ebh, sq);
    hipLaunchKernelGGL(k_edge,     dim3(16, 28, 4),   dim3(256), 0, stream, ebh, sq, edge);
    hipLaunchKernelGGL(k_final,    dim3(1),           dim3(256), 0, stream, psums, pcnts, hinge, edge, out);
}